// Round 9
// baseline (199.499 us; speedup 1.0000x reference)
//
#include <hip/hip_runtime.h>
#include <hip/hip_bf16.h>

// Problem constants
#define BATCH 4096
#define NFEAT 26
#define VOCAB 10000
#define EDIM 64
#define D0 1664          // NFEAT*EDIM
#define NUMB 13
#define IN_DIM 1677      // D0 + NUMB
#define K1PAD 1728       // 54*32, zero-padded K for GEMM1 (even # of 32-steps)
#define H1DIM 1024
#define H2DIM 512
#define H3DIM 256
#define EPS 1e-5f

typedef __attribute__((ext_vector_type(8))) short short8;
typedef __attribute__((ext_vector_type(16))) float f32x16;

#define NB_GATHER 512                            // 8 rows per block
#define NGRP ((K1PAD/16)*(H1DIM/32)*64 + (H1DIM/16)*(H2DIM/32)*64 + (H2DIM/16)*(H3DIM/32)*64)
#define NB_CVT (NGRP / 256)                      // 1184 exactly

// Raw barrier: waits LDS ops only — does NOT drain vmcnt, so prefetch
// global loads stay in flight across the barrier.
__device__ __forceinline__ void sync_lds() {
    asm volatile("s_waitcnt lgkmcnt(0)\n\ts_barrier" ::: "memory");
}

__device__ __forceinline__ void store_out(__hip_bfloat16* p, float v) { *p = __float2bfloat16(v); }
__device__ __forceinline__ void store_out(float* p, float v) { *p = v; }

// ---------------------------------------------------------------------------
// prep: one launch, three block ranges.
//  [0, 512):        embedding gather -> H0 (bn0'd bf16) + 4 dots vs x0
//  [512, 512+1184): weights fp32 -> bf16, MFMA fragment-major [verified R5-R8]
//  last block:      cross-weight column sums
// ---------------------------------------------------------------------------
__global__ __launch_bounds__(256) void prep(
    const float* __restrict__ numb, const int* __restrict__ cat,
    const float* __restrict__ emb, const float* __restrict__ bn0,
    const float* __restrict__ w1, const float* __restrict__ w2,
    const float* __restrict__ w3,
    const float* __restrict__ cw, const float* __restrict__ pw,
    __hip_bfloat16* __restrict__ W1f, __hip_bfloat16* __restrict__ W2f,
    __hip_bfloat16* __restrict__ W3f, float* __restrict__ Csums,
    float* __restrict__ Dots, __hip_bfloat16* __restrict__ H0) {
    const int bid = blockIdx.x, tid = threadIdx.x;

    if (bid < NB_GATHER) {
        __shared__ __align__(16) float sc_s[IN_DIM + 3];
        __shared__ __align__(16) float sh_s[IN_DIM + 3];
        __shared__ int idx[8][NFEAT];
        const int b0 = bid * 8;

        for (int j = tid; j < IN_DIM; j += 256) {
            float g = bn0[j], bb = bn0[IN_DIM + j], m = bn0[2 * IN_DIM + j], v = bn0[3 * IN_DIM + j];
            float s = g * rsqrtf(v + EPS);
            sc_s[j] = s;
            sh_s[j] = bb - m * s;
        }
        if (tid < 8 * NFEAT) idx[tid / NFEAT][tid % NFEAT] = cat[(b0 + tid / NFEAT) * NFEAT + tid % NFEAT];
        __syncthreads();

        const int wave = tid >> 6, lane = tid & 63;
        const float4* cw0 = (const float4*)cw;
        const float4* cw1 = (const float4*)(cw + D0);
        const float4* cw2 = (const float4*)(cw + 2 * D0);
        const float4* pw4 = (const float4*)pw;

#pragma unroll
        for (int rr = 0; rr < 2; rr++) {
            const int r = wave * 2 + rr, b = b0 + r;
            float d0 = 0.f, d1 = 0.f, d2 = 0.f, dp = 0.f;
            for (int j = lane; j < D0 / 4; j += 64) {
                int f = j >> 4, d4 = j & 15;
                float4 v = *(const float4*)&emb[((size_t)f * VOCAB + idx[r][f]) * EDIM + d4 * 4];
                float4 c0 = cw0[j], c1 = cw1[j], c2 = cw2[j], p4 = pw4[j];
                d0 += v.x * c0.x + v.y * c0.y + v.z * c0.z + v.w * c0.w;
                d1 += v.x * c1.x + v.y * c1.y + v.z * c1.z + v.w * c1.w;
                d2 += v.x * c2.x + v.y * c2.y + v.z * c2.z + v.w * c2.w;
                dp += v.x * p4.x + v.y * p4.y + v.z * p4.z + v.w * p4.w;
                float4 s = *(const float4*)&sc_s[j * 4];
                float4 t = *(const float4*)&sh_s[j * 4];
                union { __hip_bfloat16 h[4]; short4 s4; } u;
                u.h[0] = __float2bfloat16(v.x * s.x + t.x);
                u.h[1] = __float2bfloat16(v.y * s.y + t.y);
                u.h[2] = __float2bfloat16(v.z * s.z + t.z);
                u.h[3] = __float2bfloat16(v.w * s.w + t.w);
                *(short4*)&H0[(size_t)b * K1PAD + j * 4] = u.s4;
            }
            {
                int col = D0 + lane;
                float y = 0.f;
                if (col < IN_DIM) y = numb[b * NUMB + lane] * sc_s[col] + sh_s[col];
                H0[(size_t)b * K1PAD + col] = __float2bfloat16(y);
            }
            for (int o = 32; o > 0; o >>= 1) {
                d0 += __shfl_down(d0, o, 64); d1 += __shfl_down(d1, o, 64);
                d2 += __shfl_down(d2, o, 64); dp += __shfl_down(dp, o, 64);
            }
            if (lane == 0) {
                Dots[b * 4 + 0] = d0; Dots[b * 4 + 1] = d1;
                Dots[b * 4 + 2] = d2; Dots[b * 4 + 3] = dp;
            }
        }
        return;
    }

    if (bid < NB_GATHER + NB_CVT) {
        const int g1 = (K1PAD / 16) * (H1DIM / 32) * 64;
        const int g2 = (H1DIM / 16) * (H2DIM / 32) * 64;
        const int g3 = (H2DIM / 16) * (H3DIM / 32) * 64;
        int i = (bid - NB_GATHER) * 256 + tid;
        const float* src; __hip_bfloat16* dst; int N32, Ksrc;
        if (i < g1)        { src = w1; dst = W1f; N32 = H1DIM / 32; Ksrc = IN_DIM; }
        else if ((i -= g1) < g2) { src = w2; dst = W2f; N32 = H2DIM / 32; Ksrc = H1DIM; }
        else if ((i -= g2) < g3) { src = w3; dst = W3f; N32 = H3DIM / 32; Ksrc = H2DIM; }
        else return;
        const int lane = i & 63, rest = i >> 6;
        const int n32 = rest % N32, k16 = rest / N32;
        const int row = n32 * 32 + (lane & 31);
        const int kb = k16 * 16 + (lane >> 5) * 8;
        union { __hip_bfloat16 h[8]; short8 s8; } u;
#pragma unroll
        for (int j = 0; j < 8; j++) {
            int kk = kb + j;
            u.h[j] = __float2bfloat16(kk < Ksrc ? src[(size_t)row * Ksrc + kk] : 0.f);
        }
        *(short8*)&dst[(size_t)i * 8] = u.s8;
        return;
    }

    {
        __shared__ float red[4][4];
        float p0 = 0.f, p1 = 0.f, p2 = 0.f, p3 = 0.f;
        for (int j = tid; j < D0; j += 256) {
            p0 += cw[j]; p1 += cw[D0 + j]; p2 += cw[2 * D0 + j]; p3 += pw[j];
        }
        for (int o = 32; o > 0; o >>= 1) {
            p0 += __shfl_down(p0, o, 64); p1 += __shfl_down(p1, o, 64);
            p2 += __shfl_down(p2, o, 64); p3 += __shfl_down(p3, o, 64);
        }
        if ((tid & 63) == 0) {
            int w = tid >> 6;
            red[w][0] = p0; red[w][1] = p1; red[w][2] = p2; red[w][3] = p3;
        }
        __syncthreads();
        if (tid < 4) Csums[tid] = red[0][tid] + red[1][tid] + red[2][tid] + red[3][tid];
    }
}

// ---------------------------------------------------------------------------
// Helpers (explicit reg sets — R5 proved dynamic indexing -> scratch).
// ---------------------------------------------------------------------------
template <int NT>
__device__ __forceinline__ void ldgB(const short* __restrict__ Wf, int k,
                                     int NT32, int n32w, int lane,
                                     short8 (&dst)[2 * NT]) {
#pragma unroll
    for (int t = 0; t < 2; t++) {
        const short8* p = (const short8*)&Wf[(((size_t)(k * 2 + t) * NT32 + n32w) * 64 + lane) * 8];
#pragma unroll
        for (int n = 0; n < NT; n++) dst[t * NT + n] = p[(size_t)n * 64];
    }
}

template <int NT>
__device__ __forceinline__ void compute_step(const short* lAbuf, int rdoff,
                                             const short8 (&bv)[2 * NT],
                                             f32x16 (&acc)[NT]) {
#pragma unroll
    for (int t = 0; t < 2; t++) {
        short8 af = *(const short8*)&lAbuf[rdoff + t * 512];
#pragma unroll
        for (int n = 0; n < NT; n++)
            acc[n] = __builtin_amdgcn_mfma_f32_32x32x16_bf16(af, bv[t * NT + n], acc[n], 0, 0, 0);
    }
}

// ---------------------------------------------------------------------------
// M-STACKED GEMM: BM=128, BN=NT*32... here BN = NT*32 per wave with ALL 4
// waves sharing B (wave w owns rows w*32..w*32+31). Halves per-FLOP B-L2
// traffic vs the 2x2 grid. A staged fragment-order in LDS (1x redundancy).
// Block tile 128 x (NT*32). KS even >= 4.
// ---------------------------------------------------------------------------
template <int NT, typename OutT>
__global__ __launch_bounds__(256) void gemm_bn_ms(
    const short* __restrict__ A, const short* __restrict__ Wf,
    const float* __restrict__ bias, const float* __restrict__ bn,
    OutT* __restrict__ out, int M, int N, int K) {
    __shared__ short lA[2][4096];   // [m32(4)][t(2)][lh(2)][ln(32)][8]
    const int tid = threadIdx.x;
    const int wave = tid >> 6, lane = tid & 63;
    const int ln = lane & 31, lh = lane >> 5;
    const int m0 = blockIdx.y * 128, n0 = blockIdx.x * (NT * 32);
    const int NT32 = N >> 5;
    const int n32w = n0 >> 5;                      // shared by all waves
    const int KS = K / 32;

    f32x16 acc[NT] = {};

    // A staging: srow = tid>>1 (128 rows), two short8s at k-halves (tid&1)*16.
    const int srow = tid >> 1;
    const int swoff = ((srow >> 5) * 4 + (tid & 1) * 2) * 256 + (srow & 31) * 8;
    const size_t gabase = (size_t)(m0 + srow) * K + (tid & 1) * 16;
    const int rdoff = (wave * 4 + lh) * 256 + ln * 8;   // + t*512 in compute

    short8 ar0a, ar0b, ar1a, ar1b, bvA[2 * NT], bvB[2 * NT];

    ar0a = *(const short8*)&A[gabase];
    ar0b = *(const short8*)&A[gabase + 8];
    ldgB<NT>(Wf, 0, NT32, n32w, lane, bvA);
    *(short8*)&lA[0][swoff] = ar0a;
    *(short8*)&lA[0][swoff + 256] = ar0b;
    ar1a = *(const short8*)&A[gabase + 32];
    ar1b = *(const short8*)&A[gabase + 40];
    ldgB<NT>(Wf, 1, NT32, n32w, lane, bvB);
    sync_lds();

    for (int k = 0; k < KS; k += 2) {
        compute_step<NT>(lA[0], rdoff, bvA, acc);
        *(short8*)&lA[1][swoff] = ar1a;
        *(short8*)&lA[1][swoff + 256] = ar1b;
        if (k + 2 < KS) {
            ar0a = *(const short8*)&A[gabase + (size_t)(k + 2) * 32];
            ar0b = *(const short8*)&A[gabase + (size_t)(k + 2) * 32 + 8];
            ldgB<NT>(Wf, k + 2, NT32, n32w, lane, bvA);
        }
        sync_lds();
        compute_step<NT>(lA[1], rdoff, bvB, acc);
        if (k + 2 < KS) {
            *(short8*)&lA[0][swoff] = ar0a;
            *(short8*)&lA[0][swoff + 256] = ar0b;
            if (k + 3 < KS) {
                ar1a = *(const short8*)&A[gabase + (size_t)(k + 3) * 32];
                ar1b = *(const short8*)&A[gabase + (size_t)(k + 3) * 32 + 8];
                ldgB<NT>(Wf, k + 3, NT32, n32w, lane, bvB);
            }
            sync_lds();
        }
    }

    // epilogue: fused bias + BN.  C/D 32x32: col=lane&31,
    // row=(reg&3)+8*(reg>>2)+4*(lane>>5)  [verified m74/m101 + R5-R8]
    const float* g = bn;
    const float* bb = bn + N;
    const float* mm = bn + 2 * N;
    const float* vv = bn + 3 * N;
#pragma unroll
    for (int n = 0; n < NT; n++) {
        int col = n0 + n * 32 + ln;
        float sc = g[col] * rsqrtf(vv[col] + EPS);
        float sh = (bias[col] - mm[col]) * sc + bb[col];
#pragma unroll
        for (int r = 0; r < 16; r++) {
            int row = m0 + wave * 32 + (r & 3) + 8 * (r >> 2) + 4 * lh;
            store_out(&out[(size_t)row * N + col], acc[n][r] * sc + sh);
        }
    }
}

// ---------------------------------------------------------------------------
// GEMM3 fully fused tail: block = 32 rows x 256 cols (all of H3), grid 128.
// Wave w covers cols w*64..w*64+63 (NT=2); A (32 rows) shared via LDS.
// Epilogue: BN -> x pw -> in-half shuffle reduce -> LDS combine ->
// cross recursion + sigmoid -> out.  No atomics, no extra kernels.
// K=512 -> 8 chunks of 64k (4 k16 each), double-buffered.
// ---------------------------------------------------------------------------
__global__ __launch_bounds__(256) void gemm3_final(
    const short* __restrict__ A, const short* __restrict__ Wf,
    const float* __restrict__ bias, const float* __restrict__ bn,
    const float* __restrict__ pwD0,
    const float* __restrict__ Dots, const float* __restrict__ Csums,
    const float* __restrict__ cb, const float* __restrict__ pb,
    float* __restrict__ out) {
    const int N = H3DIM, K = H2DIM;
    const int NT32 = N >> 5;                     // 8
    __shared__ short lA[2][2048];                // [c(4)][lh(2)][ln(32)][8]
    __shared__ float part[4][32];
    const int tid = threadIdx.x;
    const int wave = tid >> 6, lane = tid & 63;
    const int ln = lane & 31, lh = lane >> 5;
    const int m0 = blockIdx.x * 32;
    const int n32w = wave * 2;

    f32x16 acc[2] = {};

    // A staging: thread i -> (lnr=i&31, c=(i>>5)&3, lhs=i>>7), one short8.
    const int lnr = tid & 31, cc = (tid >> 5) & 3, lhs = tid >> 7;
    const int swoff = (cc * 2 + lhs) * 256 + lnr * 8;
    const size_t gabase = (size_t)(m0 + lnr) * K + cc * 16 + lhs * 8;
    const int rdoff = lh * 256 + ln * 8;         // + c*512 per k16

    short8 ar0, ar1, bvA[8], bvB[8];

    auto ldgB3 = [&](int kc, short8 (&dst)[8]) {
#pragma unroll
        for (int c = 0; c < 4; c++) {
            const short8* p = (const short8*)&Wf[(((size_t)(kc * 4 + c) * NT32 + n32w) * 64 + lane) * 8];
#pragma unroll
            for (int n = 0; n < 2; n++) dst[c * 2 + n] = p[(size_t)n * 64];
        }
    };
    auto comp = [&](const short* buf, const short8 (&bv)[8]) {
#pragma unroll
        for (int c = 0; c < 4; c++) {
            short8 af = *(const short8*)&buf[rdoff + c * 512];
#pragma unroll
            for (int n = 0; n < 2; n++)
                acc[n] = __builtin_amdgcn_mfma_f32_32x32x16_bf16(af, bv[c * 2 + n], acc[n], 0, 0, 0);
        }
    };

    ar0 = *(const short8*)&A[gabase];
    ldgB3(0, bvA);
    *(short8*)&lA[0][swoff] = ar0;
    ar1 = *(const short8*)&A[gabase + 64];
    ldgB3(1, bvB);
    sync_lds();

#pragma unroll
    for (int kc = 0; kc < 8; kc += 2) {
        comp(lA[0], bvA);
        *(short8*)&lA[1][swoff] = ar1;
        if (kc + 2 < 8) {
            ar0 = *(const short8*)&A[gabase + (size_t)(kc + 2) * 64];
            ldgB3(kc + 2, bvA);
        }
        sync_lds();
        comp(lA[1], bvB);
        if (kc + 2 < 8) {
            *(short8*)&lA[0][swoff] = ar0;
            if (kc + 3 < 8) {
                ar1 = *(const short8*)&A[gabase + (size_t)(kc + 3) * 64];
                ldgB3(kc + 3, bvB);
            }
            sync_lds();
        }
    }

    // epilogue
    const float* g = bn;
    const float* bb = bn + N;
    const float* mm = bn + 2 * N;
    const float* vv = bn + 3 * N;
    float sc[2], sh[2], pwc[2];
#pragma unroll
    for (int n = 0; n < 2; n++) {
        int col = wave * 64 + n * 32 + ln;
        sc[n] = g[col] * rsqrtf(vv[col] + EPS);
        sh[n] = (bias[col] - mm[col]) * sc[n] + bb[col];
        pwc[n] = pwD0[col];
    }
#pragma unroll
    for (int r = 0; r < 16; r++) {
        float v = (acc[0][r] * sc[0] + sh[0]) * pwc[0]
                + (acc[1][r] * sc[1] + sh[1]) * pwc[1];
#pragma unroll
        for (int o = 1; o <= 16; o <<= 1) v += __shfl_xor(v, o, 64);
        if (ln == 0) {
            int row = (r & 3) + 8 * (r >> 2) + 4 * lh;
            part[wave][row] = v;
        }
    }
    __syncthreads();
    if (tid < 32) {
        const int b = m0 + tid;
        float z = part[0][tid] + part[1][tid] + part[2][tid] + part[3][tid];
        float P = 1.f, Q = 0.f;
#pragma unroll
        for (int i = 0; i < 3; i++) {
            float s = 1.f + P * Dots[b * 4 + i] + Q * Csums[i];
            P = s * P;
            Q = s * Q + cb[i];
        }
        float zz = P * Dots[b * 4 + 3] + Q * Csums[3] + z + pb[0];
        out[b] = 1.f / (1.f + expf(-zz));
    }
}

// ---------------------------------------------------------------------------
extern "C" void kernel_launch(void* const* d_in, const int* in_sizes, int n_in,
                              void* d_out, int out_size, void* d_ws, size_t ws_size,
                              hipStream_t stream) {
    const float* numb = (const float*)d_in[0];
    const int* cat = (const int*)d_in[1];
    const float* emb = (const float*)d_in[2];
    const float* bn0 = (const float*)d_in[3];
    const float* w1 = (const float*)d_in[4];
    const float* b1 = (const float*)d_in[5];
    const float* bn1 = (const float*)d_in[6];
    const float* w2 = (const float*)d_in[7];
    const float* b2 = (const float*)d_in[8];
    const float* bn2 = (const float*)d_in[9];
    const float* w3 = (const float*)d_in[10];
    const float* b3 = (const float*)d_in[11];
    const float* bn3 = (const float*)d_in[12];
    const float* cw = (const float*)d_in[13];
    const float* cb = (const float*)d_in[14];
    const float* pw = (const float*)d_in[15];
    const float* pb = (const float*)d_in[16];
    float* out = (float*)d_out;

    char* ws = (char*)d_ws;
    __hip_bfloat16* H0  = (__hip_bfloat16*)(ws + 0);          // 4096*1728*2 = 14,155,776
    __hip_bfloat16* W1f = (__hip_bfloat16*)(ws + 14155776);   // 1728*1024*2 =  3,538,944
    __hip_bfloat16* H1  = (__hip_bfloat16*)(ws + 17694720);   // 4096*1024*2 =  8,388,608
    __hip_bfloat16* W2f = (__hip_bfloat16*)(ws + 26083328);   // 1024*512*2  =  1,048,576
    __hip_bfloat16* H2  = (__hip_bfloat16*)(ws + 27131904);   // 4096*512*2  =  4,194,304
    __hip_bfloat16* W3f = (__hip_bfloat16*)(ws + 31326208);   //  512*256*2  =    262,144
    float* Dots         = (float*)(ws + 31588352);            // 4096*4*4    =     65,536
    float* Csums        = (float*)(ws + 31653888);            // pad 256
    // total 31,654,144 bytes

    // prep: gather(512) + convert(1184) + tail(1)
    prep<<<NB_GATHER + NB_CVT + 1, 256, 0, stream>>>(
        numb, cat, emb, bn0, w1, w2, w3, cw, pw,
        W1f, W2f, W3f, Csums, Dots, H0);

    // GEMM1: 4096x1024 @ K=1728, M-stack BM=128 BN=64 (NT=2) -> 512 blocks
    gemm_bn_ms<2, __hip_bfloat16>
        <<<dim3(H1DIM / 64, BATCH / 128), 256, 0, stream>>>(
            (const short*)H0, (const short*)W1f, b1, bn1, H1, BATCH, H1DIM, K1PAD);

    // GEMM2: 4096x512 @ K=1024, M-stack BM=128 BN=32 (NT=1) -> 512 blocks
    gemm_bn_ms<1, __hip_bfloat16>
        <<<dim3(H2DIM / 32, BATCH / 128), 256, 0, stream>>>(
            (const short*)H1, (const short*)W2f, b2, bn2, H2, BATCH, H2DIM, H1DIM);

    // GEMM3 + BN + pred-dot + cross + sigmoid, fully fused -> 128 blocks
    gemm3_final<<<BATCH / 32, 256, 0, stream>>>(
        (const short*)H2, (const short*)W3f, b3, bn3, pw + D0,
        Dots, Csums, cb, pb, out);
}

// Round 10
// 197.553 us; speedup vs baseline: 1.0098x; 1.0098x over previous
//
#include <hip/hip_runtime.h>
#include <hip/hip_bf16.h>

// Problem constants
#define BATCH 4096
#define NFEAT 26
#define VOCAB 10000
#define EDIM 64
#define D0 1664          // NFEAT*EDIM
#define NUMB 13
#define IN_DIM 1677      // D0 + NUMB
#define K1PAD 1728       // 54*32, zero-padded K for GEMM1 (even # of 32-steps)
#define H1DIM 1024
#define H2DIM 512
#define H3DIM 256
#define EPS 1e-5f

typedef __attribute__((ext_vector_type(8))) short short8;
typedef __attribute__((ext_vector_type(16))) float f32x16;

#define NB_GATHER 512                            // 8 rows per block
#define NGRP ((K1PAD/16)*(H1DIM/32)*64 + (H1DIM/16)*(H2DIM/32)*64 + (H2DIM/16)*(H3DIM/32)*64)
#define NB_CVT (NGRP / 256)                      // 1184 exactly

// Raw barrier: waits LDS ops only — does NOT drain vmcnt, so prefetch
// global loads stay in flight across the barrier.
__device__ __forceinline__ void sync_lds() {
    asm volatile("s_waitcnt lgkmcnt(0)\n\ts_barrier" ::: "memory");
}

__device__ __forceinline__ void store_out(__hip_bfloat16* p, float v) { *p = __float2bfloat16(v); }
__device__ __forceinline__ void store_out(float* p, float v) { *p = v; }

// ---------------------------------------------------------------------------
// prep: one launch, three block ranges.
//  [0, 512):        embedding gather -> H0 (bn0'd bf16) + 4 dots vs x0
//  [512, 512+1184): weights fp32 -> bf16, MFMA fragment-major [verified R5-R9]
//  last block:      cross-weight column sums + Zacc zero-init
// ---------------------------------------------------------------------------
__global__ __launch_bounds__(256) void prep(
    const float* __restrict__ numb, const int* __restrict__ cat,
    const float* __restrict__ emb, const float* __restrict__ bn0,
    const float* __restrict__ w1, const float* __restrict__ w2,
    const float* __restrict__ w3,
    const float* __restrict__ cw, const float* __restrict__ pw,
    __hip_bfloat16* __restrict__ W1f, __hip_bfloat16* __restrict__ W2f,
    __hip_bfloat16* __restrict__ W3f, float* __restrict__ Csums,
    float* __restrict__ Zacc, float* __restrict__ Dots,
    __hip_bfloat16* __restrict__ H0) {
    const int bid = blockIdx.x, tid = threadIdx.x;

    if (bid < NB_GATHER) {
        // ---- gather + bn0 + 4 dots (8 rows/block, 1 wave per 2 rows) ----
        __shared__ __align__(16) float sc_s[IN_DIM + 3];
        __shared__ __align__(16) float sh_s[IN_DIM + 3];
        __shared__ int idx[8][NFEAT];
        const int b0 = bid * 8;

        for (int j = tid; j < IN_DIM; j += 256) {
            float g = bn0[j], bb = bn0[IN_DIM + j], m = bn0[2 * IN_DIM + j], v = bn0[3 * IN_DIM + j];
            float s = g * rsqrtf(v + EPS);
            sc_s[j] = s;
            sh_s[j] = bb - m * s;
        }
        if (tid < 8 * NFEAT) idx[tid / NFEAT][tid % NFEAT] = cat[(b0 + tid / NFEAT) * NFEAT + tid % NFEAT];
        __syncthreads();

        const int wave = tid >> 6, lane = tid & 63;
        const float4* cw0 = (const float4*)cw;
        const float4* cw1 = (const float4*)(cw + D0);
        const float4* cw2 = (const float4*)(cw + 2 * D0);
        const float4* pw4 = (const float4*)pw;

#pragma unroll
        for (int rr = 0; rr < 2; rr++) {
            const int r = wave * 2 + rr, b = b0 + r;
            float d0 = 0.f, d1 = 0.f, d2 = 0.f, dp = 0.f;
            for (int j = lane; j < D0 / 4; j += 64) {
                int f = j >> 4, d4 = j & 15;
                float4 v = *(const float4*)&emb[((size_t)f * VOCAB + idx[r][f]) * EDIM + d4 * 4];
                float4 c0 = cw0[j], c1 = cw1[j], c2 = cw2[j], p4 = pw4[j];
                d0 += v.x * c0.x + v.y * c0.y + v.z * c0.z + v.w * c0.w;
                d1 += v.x * c1.x + v.y * c1.y + v.z * c1.z + v.w * c1.w;
                d2 += v.x * c2.x + v.y * c2.y + v.z * c2.z + v.w * c2.w;
                dp += v.x * p4.x + v.y * p4.y + v.z * p4.z + v.w * p4.w;
                float4 s = *(const float4*)&sc_s[j * 4];
                float4 t = *(const float4*)&sh_s[j * 4];
                union { __hip_bfloat16 h[4]; short4 s4; } u;
                u.h[0] = __float2bfloat16(v.x * s.x + t.x);
                u.h[1] = __float2bfloat16(v.y * s.y + t.y);
                u.h[2] = __float2bfloat16(v.z * s.z + t.z);
                u.h[3] = __float2bfloat16(v.w * s.w + t.w);
                *(short4*)&H0[(size_t)b * K1PAD + j * 4] = u.s4;
            }
            // numb tail + zero pad: cols D0..K1PAD (64 cols, one per lane)
            {
                int col = D0 + lane;
                float y = 0.f;
                if (col < IN_DIM) y = numb[b * NUMB + lane] * sc_s[col] + sh_s[col];
                H0[(size_t)b * K1PAD + col] = __float2bfloat16(y);
            }
            for (int o = 32; o > 0; o >>= 1) {
                d0 += __shfl_down(d0, o, 64); d1 += __shfl_down(d1, o, 64);
                d2 += __shfl_down(d2, o, 64); dp += __shfl_down(dp, o, 64);
            }
            if (lane == 0) {
                Dots[b * 4 + 0] = d0; Dots[b * 4 + 1] = d1;
                Dots[b * 4 + 2] = d2; Dots[b * 4 + 3] = dp;
            }
        }
        return;
    }

    if (bid < NB_GATHER + NB_CVT) {
        // ---- weight convert to fragment-major bf16 ----
        const int g1 = (K1PAD / 16) * (H1DIM / 32) * 64;
        const int g2 = (H1DIM / 16) * (H2DIM / 32) * 64;
        const int g3 = (H2DIM / 16) * (H3DIM / 32) * 64;
        int i = (bid - NB_GATHER) * 256 + tid;
        const float* src; __hip_bfloat16* dst; int N32, Ksrc;
        if (i < g1)        { src = w1; dst = W1f; N32 = H1DIM / 32; Ksrc = IN_DIM; }
        else if ((i -= g1) < g2) { src = w2; dst = W2f; N32 = H2DIM / 32; Ksrc = H1DIM; }
        else if ((i -= g2) < g3) { src = w3; dst = W3f; N32 = H3DIM / 32; Ksrc = H2DIM; }
        else return;
        const int lane = i & 63, rest = i >> 6;
        const int n32 = rest % N32, k16 = rest / N32;
        const int row = n32 * 32 + (lane & 31);
        const int kb = k16 * 16 + (lane >> 5) * 8;
        union { __hip_bfloat16 h[8]; short8 s8; } u;
#pragma unroll
        for (int j = 0; j < 8; j++) {
            int kk = kb + j;
            u.h[j] = __float2bfloat16(kk < Ksrc ? src[(size_t)row * Ksrc + kk] : 0.f);
        }
        *(short8*)&dst[(size_t)i * 8] = u.s8;
        return;
    }

    // ---- last block: Csums + Zacc zero ----
    {
        __shared__ float red[4][4];
        for (int j = tid; j < BATCH; j += 256) Zacc[j] = 0.f;
        float p0 = 0.f, p1 = 0.f, p2 = 0.f, p3 = 0.f;
        for (int j = tid; j < D0; j += 256) {
            p0 += cw[j]; p1 += cw[D0 + j]; p2 += cw[2 * D0 + j]; p3 += pw[j];
        }
        for (int o = 32; o > 0; o >>= 1) {
            p0 += __shfl_down(p0, o, 64); p1 += __shfl_down(p1, o, 64);
            p2 += __shfl_down(p2, o, 64); p3 += __shfl_down(p3, o, 64);
        }
        if ((tid & 63) == 0) {
            int w = tid >> 6;
            red[w][0] = p0; red[w][1] = p1; red[w][2] = p2; red[w][3] = p3;
        }
        __syncthreads();
        if (tid < 4) Csums[tid] = red[0][tid] + red[1][tid] + red[2][tid] + red[3][tid];
    }
}

// ---------------------------------------------------------------------------
// GEMM helpers: explicit double-buffer register sets (R5 proved dynamic
// VGPR-array indexing demotes to scratch — all indices const after unroll).
// ---------------------------------------------------------------------------
template <int NT>
__device__ __forceinline__ void ldgB(const short* __restrict__ Wf, int k,
                                     int NT32, int n32w, int lane,
                                     short8 (&dst)[2 * NT]) {
#pragma unroll
    for (int t = 0; t < 2; t++) {
        const short8* p = (const short8*)&Wf[(((size_t)(k * 2 + t) * NT32 + n32w) * 64 + lane) * 8];
#pragma unroll
        for (int n = 0; n < NT; n++) dst[t * NT + n] = p[(size_t)n * 64];
    }
}

template <int NT>
__device__ __forceinline__ void compute_step(const short* lAbuf, int rdoff,
                                             const short8 (&bv)[2 * NT],
                                             f32x16 (&acc)[NT]) {
#pragma unroll
    for (int t = 0; t < 2; t++) {
        short8 af = *(const short8*)&lAbuf[rdoff + t * 512];
#pragma unroll
        for (int n = 0; n < NT; n++)
            acc[n] = __builtin_amdgcn_mfma_f32_32x32x16_bf16(af, bv[t * NT + n], acc[n], 0, 0, 0);
    }
}

// ---------------------------------------------------------------------------
// GEMM, B-from-global: C = A(MxK) @ W(NxK)^T, epilogue bias + BN.
// BM=64, BN=NT*64. 4 waves 2(M)x2(N); wave tile 32 x NT*32, 32x32x16 MFMA.
// A staged global->VGPR->LDS fragment-order (conflict-free), double-buffered,
// 2x-unrolled K loop; B direct from global (fragment-major, L2-resident),
// double-buffered in regs. KS even, >= 4.  [verified R6-R8; best config R8]
// ---------------------------------------------------------------------------
template <int NT, typename OutT>
__global__ __launch_bounds__(256) void gemm_bn_bg(
    const short* __restrict__ A, const short* __restrict__ Wf,
    const float* __restrict__ bias, const float* __restrict__ bn,
    OutT* __restrict__ out, int M, int N, int K) {
    __shared__ short lA[2][2048];
    const int tid = threadIdx.x;
    const int wave = tid >> 6, lane = tid & 63;
    const int wm = wave >> 1, wn = wave & 1;
    const int ln = lane & 31, lh = lane >> 5;
    const int m0 = blockIdx.y * 64, n0 = blockIdx.x * (NT * 64);
    const int NT32 = N >> 5;
    const int n32w = (n0 >> 5) + wn * NT;
    const int KS = K / 32;

    f32x16 acc[NT] = {};

    const int srow = tid >> 2;
    const int swoff = ((srow >> 5) * 4 + ((tid >> 1) & 1) * 2 + (tid & 1)) * 256 + (srow & 31) * 8;
    const size_t gabase = (size_t)(m0 + srow) * K + (tid & 3) * 8;
    const int rdoff = (wm * 4 + lh) * 256 + ln * 8;

    short8 ar0, ar1, bvA[2 * NT], bvB[2 * NT];

    ar0 = *(const short8*)&A[gabase];
    ldgB<NT>(Wf, 0, NT32, n32w, lane, bvA);
    *(short8*)&lA[0][swoff] = ar0;
    ar1 = *(const short8*)&A[gabase + 32];
    ldgB<NT>(Wf, 1, NT32, n32w, lane, bvB);
    sync_lds();

    for (int k = 0; k < KS; k += 2) {
        compute_step<NT>(lA[0], rdoff, bvA, acc);
        *(short8*)&lA[1][swoff] = ar1;
        if (k + 2 < KS) {
            ar0 = *(const short8*)&A[gabase + (size_t)(k + 2) * 32];
            ldgB<NT>(Wf, k + 2, NT32, n32w, lane, bvA);
        }
        sync_lds();
        compute_step<NT>(lA[1], rdoff, bvB, acc);
        if (k + 2 < KS) {
            *(short8*)&lA[0][swoff] = ar0;
            if (k + 3 < KS) {
                ar1 = *(const short8*)&A[gabase + (size_t)(k + 3) * 32];
                ldgB<NT>(Wf, k + 3, NT32, n32w, lane, bvB);
            }
            sync_lds();
        }
    }

    // epilogue: fused bias + BN.  C/D 32x32: col=lane&31,
    // row=(reg&3)+8*(reg>>2)+4*(lane>>5)  [verified m74/m101 + R5-R9]
    const float* g = bn;
    const float* bb = bn + N;
    const float* mm = bn + 2 * N;
    const float* vv = bn + 3 * N;
#pragma unroll
    for (int n = 0; n < NT; n++) {
        int col = n0 + wn * NT * 32 + n * 32 + ln;
        float sc = g[col] * rsqrtf(vv[col] + EPS);
        float sh = (bias[col] - mm[col]) * sc + bb[col];
#pragma unroll
        for (int r = 0; r < 16; r++) {
            int row = m0 + wm * 32 + (r & 3) + 8 * (r >> 2) + 4 * lh;
            store_out(&out[(size_t)row * N + col], acc[n][r] * sc + sh);
        }
    }
}

// ---------------------------------------------------------------------------
// GEMM3 + pred-dot fusion: H3 = BN(H2@W3^T + b3) never materialized;
// epilogue computes (H3[row][col] * pw[D0+col]) reduced over this block's
// 64 cols and atomicAdd'ed into Zacc[row].  BM=64, BN=64 (NT=1).
// ---------------------------------------------------------------------------
__global__ __launch_bounds__(256) void gemm3_pred(
    const short* __restrict__ A, const short* __restrict__ Wf,
    const float* __restrict__ bias, const float* __restrict__ bn,
    const float* __restrict__ pwD0, float* __restrict__ Zacc,
    int M, int N, int K) {
    __shared__ short lA[2][2048];
    const int tid = threadIdx.x;
    const int wave = tid >> 6, lane = tid & 63;
    const int wm = wave >> 1, wn = wave & 1;
    const int ln = lane & 31, lh = lane >> 5;
    const int m0 = blockIdx.y * 64, n0 = blockIdx.x * 64;
    const int NT32 = N >> 5;
    const int n32w = (n0 >> 5) + wn;
    const int KS = K / 32;

    f32x16 acc[1] = {};

    const int srow = tid >> 2;
    const int swoff = ((srow >> 5) * 4 + ((tid >> 1) & 1) * 2 + (tid & 1)) * 256 + (srow & 31) * 8;
    const size_t gabase = (size_t)(m0 + srow) * K + (tid & 3) * 8;
    const int rdoff = (wm * 4 + lh) * 256 + ln * 8;

    short8 ar0, ar1, bvA[2], bvB[2];

    ar0 = *(const short8*)&A[gabase];
    ldgB<1>(Wf, 0, NT32, n32w, lane, bvA);
    *(short8*)&lA[0][swoff] = ar0;
    ar1 = *(const short8*)&A[gabase + 32];
    ldgB<1>(Wf, 1, NT32, n32w, lane, bvB);
    sync_lds();

    for (int k = 0; k < KS; k += 2) {
        compute_step<1>(lA[0], rdoff, bvA, acc);
        *(short8*)&lA[1][swoff] = ar1;
        if (k + 2 < KS) {
            ar0 = *(const short8*)&A[gabase + (size_t)(k + 2) * 32];
            ldgB<1>(Wf, k + 2, NT32, n32w, lane, bvA);
        }
        sync_lds();
        compute_step<1>(lA[1], rdoff, bvB, acc);
        if (k + 2 < KS) {
            *(short8*)&lA[0][swoff] = ar0;
            if (k + 3 < KS) {
                ar1 = *(const short8*)&A[gabase + (size_t)(k + 3) * 32];
                ldgB<1>(Wf, k + 3, NT32, n32w, lane, bvB);
            }
            sync_lds();
        }
    }

    // epilogue: BN then dot with pw, 32-lane shuffle reduce, atomicAdd.
    const float* g = bn;
    const float* bb = bn + N;
    const float* mm = bn + 2 * N;
    const float* vv = bn + 3 * N;
    const int col = n0 + wn * 32 + ln;
    const float sc = g[col] * rsqrtf(vv[col] + EPS);
    const float sh = (bias[col] - mm[col]) * sc + bb[col];
    const float pwc = pwD0[col];
#pragma unroll
    for (int r = 0; r < 16; r++) {
        float v = (acc[0][r] * sc + sh) * pwc;
#pragma unroll
        for (int o = 1; o <= 16; o <<= 1) v += __shfl_xor(v, o, 64);
        if (ln == 0) {
            int row = m0 + wm * 32 + (r & 3) + 8 * (r >> 2) + 4 * lh;
            atomicAdd(&Zacc[row], v);
        }
    }
}

// ---------------------------------------------------------------------------
// final: cross scalar recursion + Zacc + sigmoid. One thread per row.
// ---------------------------------------------------------------------------
__global__ __launch_bounds__(256) void final_small(
    const float* __restrict__ Dots, const float* __restrict__ Csums,
    const float* __restrict__ cb, const float* __restrict__ Zacc,
    const float* __restrict__ pb, float* __restrict__ out) {
    const int b = blockIdx.x * 256 + threadIdx.x;
    float P = 1.f, Q = 0.f;
#pragma unroll
    for (int i = 0; i < 3; i++) {
        float s = 1.f + P * Dots[b * 4 + i] + Q * Csums[i];
        P = s * P;
        Q = s * Q + cb[i];
    }
    float z = P * Dots[b * 4 + 3] + Q * Csums[3] + Zacc[b] + pb[0];
    out[b] = 1.f / (1.f + expf(-z));
}

// ---------------------------------------------------------------------------
extern "C" void kernel_launch(void* const* d_in, const int* in_sizes, int n_in,
                              void* d_out, int out_size, void* d_ws, size_t ws_size,
                              hipStream_t stream) {
    const float* numb = (const float*)d_in[0];
    const int* cat = (const int*)d_in[1];
    const float* emb = (const float*)d_in[2];
    const float* bn0 = (const float*)d_in[3];
    const float* w1 = (const float*)d_in[4];
    const float* b1 = (const float*)d_in[5];
    const float* bn1 = (const float*)d_in[6];
    const float* w2 = (const float*)d_in[7];
    const float* b2 = (const float*)d_in[8];
    const float* bn2 = (const float*)d_in[9];
    const float* w3 = (const float*)d_in[10];
    const float* b3 = (const float*)d_in[11];
    const float* bn3 = (const float*)d_in[12];
    const float* cw = (const float*)d_in[13];
    const float* cb = (const float*)d_in[14];
    const float* pw = (const float*)d_in[15];
    const float* pb = (const float*)d_in[16];
    float* out = (float*)d_out;

    char* ws = (char*)d_ws;
    // workspace layout (bytes)
    __hip_bfloat16* H0  = (__hip_bfloat16*)(ws + 0);          // 4096*1728*2 = 14,155,776
    __hip_bfloat16* W1f = (__hip_bfloat16*)(ws + 14155776);   // 1728*1024*2 =  3,538,944
    __hip_bfloat16* H1  = (__hip_bfloat16*)(ws + 17694720);   // 4096*1024*2 =  8,388,608
    __hip_bfloat16* W2f = (__hip_bfloat16*)(ws + 26083328);   // 1024*512*2  =  1,048,576
    __hip_bfloat16* H2  = (__hip_bfloat16*)(ws + 27131904);   // 4096*512*2  =  4,194,304
    __hip_bfloat16* W3f = (__hip_bfloat16*)(ws + 31326208);   //  512*256*2  =    262,144
    float* Dots         = (float*)(ws + 31588352);            // 4096*4*4    =     65,536
    float* Csums        = (float*)(ws + 31653888);            // pad 256
    float* Zacc         = (float*)(ws + 31654144);            // 4096*4      =     16,384
    // total 31,670,528 bytes

    // prep: gather(512) + convert(1184) + tail(1) = 1697 blocks
    prep<<<NB_GATHER + NB_CVT + 1, 256, 0, stream>>>(
        numb, cat, emb, bn0, w1, w2, w3, cw, pw,
        W1f, W2f, W3f, Csums, Zacc, Dots, H0);

    // GEMM1: 4096x1024 @ K=1728, BM=64 BN=128 (NT=2) -> 512 blocks (2/CU)
    gemm_bn_bg<2, __hip_bfloat16>
        <<<dim3(H1DIM / 128, BATCH / 64), 256, 0, stream>>>(
            (const short*)H0, (const short*)W1f, b1, bn1, H1, BATCH, H1DIM, K1PAD);

    // GEMM2: 4096x512 @ K=1024, BM=64 BN=64 (NT=1) -> 512 blocks (2/CU)
    gemm_bn_bg<1, __hip_bfloat16>
        <<<dim3(H2DIM / 64, BATCH / 64), 256, 0, stream>>>(
            (const short*)H1, (const short*)W2f, b2, bn2, H2, BATCH, H2DIM, H1DIM);

    // GEMM3 + pred-dot: 4096x256 @ K=512 -> 256 blocks, H3 never materialized
    gemm3_pred<<<dim3(H3DIM / 64, BATCH / 64), 256, 0, stream>>>(
        (const short*)H2, (const short*)W3f, b3, bn3, pw + D0, Zacc,
        BATCH, H3DIM, H2DIM);

    final_small<<<BATCH / 256, 256, 0, stream>>>(Dots, Csums, cb, Zacc, pb, out);
}